// Round 10
// baseline (111.630 us; speedup 1.0000x reference)
//
#include <hip/hip_runtime.h>
#include <cstdint>
#include <cstddef>

// Problem constants (from reference)
#define B_SZ   512
#define DIN    256
#define DOUT   256
#define KNOTS  64
#define NK     63                 // intervals = KNOTS-1
#define HSTEP  (4.0f / 63.0f)
#define INV_H  15.75f             // exact in f32

#define IQ     64                 // input dims per forward block (4 quarters)
#define ESTR   65                 // ents row stride (entries): 65*2 mod 32 = 2
                                  // -> prologue writes 4-way (1.58x, ok), reads
                                  // bank = 2k mod 32 (inherent to random gather)

typedef _Float16 h2f __attribute__((ext_vector_type(2)));

// Per-interval entry: {y0, y1-y0, h*m0, h*m1} as 4 x f16 = 8 B (LDS-resident).
struct __align__(8) Ent { h2f ydy; h2f hmm; };
static_assert(sizeof(Ent) == 8, "Ent must be 8 bytes");

#if defined(__has_builtin)
#  if __has_builtin(__builtin_amdgcn_fdot2)
#    define HAVE_FDOT2 1
#  endif
#endif

static __device__ __forceinline__ float dot2acc(h2f a, h2f b, float acc) {
#ifdef HAVE_FDOT2
    return __builtin_amdgcn_fdot2(a, b, acc, false);
#else
    return acc + (float)a.x * (float)b.x + (float)a.y * (float)b.y;
#endif
}

static __device__ __forceinline__ unsigned f16bits(float v) {
    return (unsigned)__builtin_bit_cast(unsigned short, (_Float16)v);
}

// ---- PCHIP slope helpers (reference semantics, f32 exact) ----
static __device__ __forceinline__ float pchip_edge(float dA, float dB) {
    float m = 0.5f * (3.0f * dA - dB);
    if (m * dA <= 0.0f) {
        m = 0.0f;
    } else if (dA * dB < 0.0f && fabsf(m) > 3.0f * fabsf(dA)) {
        m = 3.0f * dA;
    }
    return m;
}

static __device__ __forceinline__ float pchip_inner(float d0, float d1) {
    if (d0 * d1 > 0.0f) {
        float denom = d0 + d1;
        if (fabsf(denom) < 1e-12f) return 0.0f;
        return 2.0f * d0 * d1 / denom;
    }
    return 0.0f;
}

// ---- Kernel A: packed per-(b,i) records + out = bias ----
// W[i*512 + b] = uint2{ (h01<<16)|k , (h11<<16)|h10 }  (8 B, 1 MB total).
// x-read is perfectly coalesced (g = b*256+i is x's own layout); W store is
// scattered (stride 2 KB) but stores don't stall.
__global__ __launch_bounds__(256) void prep_w(const float* __restrict__ x,
                                              uint2* __restrict__ W,
                                              const float* __restrict__ bias,
                                              float* __restrict__ out) {
    const int g = blockIdx.x * 256 + threadIdx.x;   // 0..131071 = b*256 + i
    const int b = g >> 8;
    const int i = g & 255;

    float xv = x[g];                                // coalesced
    float xc = fminf(fmaxf(xv, -2.0f), 2.0f);
    float tv = (xc + 2.0f) * INV_H;
    int k = (int)tv;                                // tv >= 0
    k = k > NK - 1 ? NK - 1 : k;
    float u   = tv - (float)k;
    float u2  = u * u;
    float um1 = u - 1.0f;
    float c1  = u2 * (3.0f - 2.0f * u);             // h01
    float c2  = u * um1 * um1;                      // h10
    float c3  = u2 * um1;                           // h11

    uint2 w;
    w.x = (f16bits(c1) << 16) | (unsigned)k;
    w.y = (f16bits(c3) << 16) | f16bits(c2);
    W[i * 512 + b] = w;

    out[g] = bias[i];                               // out[b][o=i-pattern] ✓ coalesced
}

// ---- Kernel B: forward — LDS Ent table, 6-instruction inner loop ----
// Grid 1024 = 256 o x 4 i-quarters; 512 threads = one sample b each.
// LDS 33 KB -> 4 blocks/CU = 8 waves/SIMD (max occupancy) to overlap the
// serialized LDS-gather, the L2 W-stream, and VALU.
// Inner loop per term: uint2 load (coalesced, L2-resident 1 MB W), v_and (k),
// v_and_or (rebuild {1,h01}), v_lshl + ds_read_b64 offset:il*520 (imm),
// 2x v_dot2_f32_f16.
__global__ __launch_bounds__(512, 8) void kan_fwd(const uint2* __restrict__ W,
                                                  const float* __restrict__ y,
                                                  float* __restrict__ out) {
    __shared__ Ent ents[IQ * ESTR];        // 33,280 B

    const int bid = blockIdx.x;
    const int o   = bid >> 2;              // 0..255
    const int iq  = bid & 3;               // i-quarter
    const int t   = threadIdx.x;

    // ---- Prologue: build Ent table, 8 threads per input dim ----
    {
        const int il = t >> 3;             // 0..63
        const int q  = t & 7;              // strip
        const int k0 = q * 8;
        const int ig = iq * IQ + il;
        const float* row = y + ((size_t)ig * DOUT + o) * KNOTS;

        float ys[11];                      // y[k0-1 .. k0+9], clamped
#pragma unroll
        for (int u = 0; u < 11; ++u) {
            int kk = k0 - 1 + u;
            kk = kk < 0 ? 0 : (kk > KNOTS - 1 ? KNOTS - 1 : kk);
            ys[u] = row[kk];               // scalar; lines L1-cached
        }
        float dd[10];                      // dd[u] = d[k0-1+u]
#pragma unroll
        for (int u = 0; u < 10; ++u) dd[u] = (ys[u + 1] - ys[u]) * INV_H;

        const int cnt = (q == 7) ? 7 : 8;  // last strip ends at k=62
#pragma unroll
        for (int n = 0; n < 8; ++n) {
            if (n < cnt) {
                const int k = k0 + n;
                float d_m1 = dd[n];        // d[k-1] (0-dup at k=0, overridden)
                float d_0  = dd[n + 1];    // d[k]
                float d_p1 = dd[n + 2];    // d[k+1] (0-dup at k=62, overridden)
                float mk  = pchip_inner(d_m1, d_0);
                if (k == 0)      mk  = pchip_edge(d_0, d_p1);
                float mk1 = pchip_inner(d_0, d_p1);
                if (k == NK - 1) mk1 = pchip_edge(d_0, d_m1);
                float y0 = ys[n + 1];
                float y1 = ys[n + 2];
                Ent e;
                e.ydy.x = (_Float16)y0;
                e.ydy.y = (_Float16)(y1 - y0);
                e.hmm.x = (_Float16)(HSTEP * mk);
                e.hmm.y = (_Float16)(HSTEP * mk1);
                ents[il * ESTR + k] = e;
            }
        }
    }
    __syncthreads();

    // ---- Main loop: one sample per thread, 64 terms ----
    const int b = t;
    const uint2* wp = W + (size_t)(iq * IQ) * 512 + b;

    float acc = 0.0f;
#pragma unroll 8
    for (int il = 0; il < IQ; ++il) {
        uint2 w = wp[(size_t)il * 512];             // coalesced 8 B, L2-hot
        const int k = (int)(w.x & 63u);
        h2f w01 = __builtin_bit_cast(h2f, (w.x & 0xFFFF0000u) | 0x3C00u); // {1,h01}
        h2f w23 = __builtin_bit_cast(h2f, w.y);                           // {h10,h11}
        Ent e = ents[il * ESTR + k];                // ds_read_b64, imm il-offset
        acc = dot2acc(e.ydy, w01, acc);             // y0 + dy*h01
        acc = dot2acc(e.hmm, w23, acc);             // hm0*h10 + hm1*h11
    }
    atomicAdd(&out[b * DOUT + o], acc);
}

// ---- Fallback: no-workspace path (only if ws_size is too small) ----
__global__ __launch_bounds__(256) void kan_naive(const float* __restrict__ x,
                                                 const float* __restrict__ y,
                                                 const float* __restrict__ bias,
                                                 float* __restrict__ out) {
    __shared__ int   sk[DIN];
    __shared__ float su[DIN];

    const int b   = blockIdx.x;
    const int tid = threadIdx.x;
    const float h = HSTEP;

    {
        float xv = x[b * DIN + tid];
        float xc = fminf(fmaxf(xv, -2.0f), 2.0f);
        float t  = (xc + 2.0f) / h;
        int k = (int)floorf(t);
        k = k < 0 ? 0 : (k > NK - 1 ? NK - 1 : k);
        sk[tid] = k;
        su[tid] = t - (float)k;
    }
    __syncthreads();

    const int o = tid;
    float acc = 0.0f;
    for (int i = 0; i < DIN; ++i) {
        int   k = sk[i];
        float u = su[i];
        const float* r = y + ((size_t)i * DOUT + o) * KNOTS;
        float ym1 = r[k > 0 ? k - 1 : 0];
        float y0  = r[k];
        float y1  = r[k + 1];
        float y2  = r[k < NK - 1 ? k + 2 : KNOTS - 1];
        float dm1 = (y0 - ym1) / h;
        float d0  = (y1 - y0) / h;
        float d1  = (y2 - y1) / h;
        float mk  = (k == 0)      ? pchip_edge(d0, d1)  : pchip_inner(dm1, d0);
        float mk1 = (k == NK - 1) ? pchip_edge(d0, dm1) : pchip_inner(d0, d1);
        float hm0 = h * mk, hm1 = h * mk1;
        float dy = y1 - y0;
        float c2 = 3.0f * dy - 2.0f * hm0 - hm1;
        float c3 = hm0 + hm1 - 2.0f * dy;
        acc += fmaf(u, fmaf(u, fmaf(u, c3, c2), hm0), y0);
    }
    out[b * DOUT + o] = acc + bias[o];
}

extern "C" void kernel_launch(void* const* d_in, const int* in_sizes, int n_in,
                              void* d_out, int out_size, void* d_ws, size_t ws_size,
                              hipStream_t stream) {
    const float* x    = (const float*)d_in[0];   // (B, DIN)
    const float* y    = (const float*)d_in[1];   // (DIN, DOUT, KNOTS)
    const float* bias = (const float*)d_in[2];   // (DOUT,)
    float* out        = (float*)d_out;           // (B, DOUT)

    const size_t need = (size_t)DIN * B_SZ * sizeof(uint2); // 1 MB

    if (ws_size >= need) {
        uint2* W = (uint2*)d_ws;
        prep_w<<<dim3((DIN * B_SZ) / 256), dim3(256), 0, stream>>>(x, W, bias, out);
        kan_fwd<<<dim3(DOUT * 4), dim3(512), 0, stream>>>(W, y, out);
    } else {
        kan_naive<<<dim3(B_SZ), dim3(256), 0, stream>>>(x, y, bias, out);
    }
}

// Round 11
// 107.161 us; speedup vs baseline: 1.0417x; 1.0417x over previous
//
#include <hip/hip_runtime.h>
#include <cstdint>
#include <cstddef>

// Problem constants (from reference)
#define B_SZ   512
#define DIN    256
#define DOUT   256
#define KNOTS  64
#define NK     63                 // intervals = KNOTS-1
#define HSTEP  (4.0f / 63.0f)
#define INV_H  15.75f             // exact in f32

#define IQ     64                 // input dims per forward block (4 quarters)
#define ESTR   65                 // ents row stride in f16x2 words; odd ->
                                  // gather banks (il*65+k)%32 cover ALL 32 banks
                                  // -> ~2-way avg = free (m136)

typedef _Float16 h2f __attribute__((ext_vector_type(2)));

#if defined(__has_builtin)
#  if __has_builtin(__builtin_amdgcn_fdot2)
#    define HAVE_FDOT2 1
#  endif
#endif

static __device__ __forceinline__ float dot2acc(h2f a, h2f b, float acc) {
#ifdef HAVE_FDOT2
    return __builtin_amdgcn_fdot2(a, b, acc, false);
#else
    return acc + (float)a.x * (float)b.x + (float)a.y * (float)b.y;
#endif
}

static __device__ __forceinline__ unsigned f16bits(float v) {
    return (unsigned)__builtin_bit_cast(unsigned short, (_Float16)v);
}
static __device__ __forceinline__ _Float16 b16f(unsigned v) {
    return __builtin_bit_cast(_Float16, (unsigned short)(v & 0xFFFFu));
}
static __device__ __forceinline__ unsigned packh2(float lo, float hi) {
    return f16bits(lo) | (f16bits(hi) << 16);
}

// ---- PCHIP slope helpers (reference semantics, f32 exact) ----
static __device__ __forceinline__ float pchip_edge(float dA, float dB) {
    float m = 0.5f * (3.0f * dA - dB);
    if (m * dA <= 0.0f) {
        m = 0.0f;
    } else if (dA * dB < 0.0f && fabsf(m) > 3.0f * fabsf(dA)) {
        m = 3.0f * dA;
    }
    return m;
}

static __device__ __forceinline__ float pchip_inner(float d0, float d1) {
    if (d0 * d1 > 0.0f) {
        float denom = d0 + d1;
        if (fabsf(denom) < 1e-12f) return 0.0f;
        return 2.0f * d0 * d1 / denom;
    }
    return 0.0f;
}

// ---- Kernel A: packed per-(b,i) records + out = bias ----
// W[i*512 + b] = uint2{ (h01<<16)|k , (h11<<16)|h10 }  (8 B, 1 MB total).
__global__ __launch_bounds__(256) void prep_w(const float* __restrict__ x,
                                              uint2* __restrict__ W,
                                              const float* __restrict__ bias,
                                              float* __restrict__ out) {
    const int g = blockIdx.x * 256 + threadIdx.x;   // 0..131071 = b*256 + i
    const int i = g & 255;

    float xv = x[g];                                // coalesced
    float xc = fminf(fmaxf(xv, -2.0f), 2.0f);
    float tv = (xc + 2.0f) * INV_H;
    int k = (int)tv;                                // tv >= 0
    k = k > NK - 1 ? NK - 1 : k;
    float u   = tv - (float)k;
    float u2  = u * u;
    float um1 = u - 1.0f;
    float c1  = u2 * (3.0f - 2.0f * u);             // h01
    float c2  = u * um1 * um1;                      // h10
    float c3  = u2 * um1;                           // h11

    const int b = g >> 8;
    uint2 w;
    w.x = (f16bits(c1) << 16) | (unsigned)k;
    w.y = (f16bits(c3) << 16) | f16bits(c2);
    W[i * 512 + b] = w;

    out[g] = bias[i];                               // coalesced out=bias init
}

// ---- Kernel B: forward — per-knot f16x2 LDS table, b32-pair gather ----
// Grid 1024 = 256 o x 4 i-quarters; 512 threads = one sample b each.
// LDS 16.6 KB; NO min-wave clamp (round-10's (512,8) forced VGPR=20 and
// spilled the prologue arrays to scratch -> 16 MB scratch WRITE, 46 us).
// Inner loop per term: uint2 W load (coalesced, L2-hot) + 2x ds_read_b32
// (all-bank gather, ~2-way = free) + ~5 VALU pack + 2x v_dot2_f32_f16.
__global__ __launch_bounds__(512) void kan_fwd(const uint2* __restrict__ W,
                                               const float* __restrict__ y,
                                               float* __restrict__ out) {
    __shared__ unsigned ents[IQ * ESTR];   // {y_k, h*m_k} f16x2 per knot; 16,640 B

    const int bid = blockIdx.x;
    const int o   = bid >> 2;              // 0..255
    const int iq  = bid & 3;               // i-quarter
    const int t   = threadIdx.x;

    // ---- Prologue: build per-knot table, 8 threads per input dim ----
    {
        const int il = t >> 3;             // 0..63
        const int q  = t & 7;              // strip: knots k0..k0+7
        const int k0 = q * 8;
        const int ig = iq * IQ + il;
        const float* row = y + ((size_t)ig * DOUT + o) * KNOTS;

        float ys[10];                      // y[k0-1 .. k0+8], clamped
#pragma unroll
        for (int u = 0; u < 10; ++u) {
            int kk = k0 - 1 + u;
            kk = kk < 0 ? 0 : (kk > KNOTS - 1 ? KNOTS - 1 : kk);
            ys[u] = row[kk];
        }
        float dd[9];                       // dd[u] = d[k0-1+u] (dup-clamp -> 0)
#pragma unroll
        for (int u = 0; u < 9; ++u) dd[u] = (ys[u + 1] - ys[u]) * INV_H;

#pragma unroll
        for (int n = 0; n < 8; ++n) {
            const int k = k0 + n;          // knot 0..63
            float mk = pchip_inner(dd[n], dd[n + 1]);  // inner(d[k-1], d[k])
            if (k == 0)         mk = pchip_edge(dd[1], dd[2]);
            if (k == KNOTS - 1) mk = pchip_edge(dd[7], dd[6]);
            // write banks: (il*65 + k0 + n) % 32 -> 2-way across the wave (free)
            ents[il * ESTR + k] = packh2(ys[n + 1], HSTEP * mk);
        }
    }
    __syncthreads();

    // ---- Main loop: one sample per thread, 64 terms ----
    const int b = t;
    const uint2* wp = W + (size_t)(iq * IQ) * 512 + b;

    float acc = 0.0f;
#pragma unroll 8
    for (int il = 0; il < IQ; ++il) {
        uint2 w = wp[(size_t)il * 512];             // coalesced 8 B, L2-hot
        const int k = (int)(w.x & 63u);
        unsigned e0 = ents[il * ESTR + k];          // {y0, hm0} ds_read_b32
        unsigned e1 = ents[il * ESTR + k + 1];      // {y1, hm1} ds_read_b32
        _Float16 h01 = b16f(w.x >> 16);
        h2f w01, w23;
        w01.x = (_Float16)1.0f - h01;               // h00
        w01.y = b16f(w.y);                          // h10
        w23.x = h01;                                // h01
        w23.y = b16f(w.y >> 16);                    // h11
        acc = dot2acc(__builtin_bit_cast(h2f, e0), w01, acc);  // y0*h00 + hm0*h10
        acc = dot2acc(__builtin_bit_cast(h2f, e1), w23, acc);  // y1*h01 + hm1*h11
    }
    atomicAdd(&out[b * DOUT + o], acc);
}

// ---- Fallback: no-workspace path (only if ws_size is too small) ----
__global__ __launch_bounds__(256) void kan_naive(const float* __restrict__ x,
                                                 const float* __restrict__ y,
                                                 const float* __restrict__ bias,
                                                 float* __restrict__ out) {
    __shared__ int   sk[DIN];
    __shared__ float su[DIN];

    const int b   = blockIdx.x;
    const int tid = threadIdx.x;
    const float h = HSTEP;

    {
        float xv = x[b * DIN + tid];
        float xc = fminf(fmaxf(xv, -2.0f), 2.0f);
        float t  = (xc + 2.0f) / h;
        int k = (int)floorf(t);
        k = k < 0 ? 0 : (k > NK - 1 ? NK - 1 : k);
        sk[tid] = k;
        su[tid] = t - (float)k;
    }
    __syncthreads();

    const int o = tid;
    float acc = 0.0f;
    for (int i = 0; i < DIN; ++i) {
        int   k = sk[i];
        float u = su[i];
        const float* r = y + ((size_t)i * DOUT + o) * KNOTS;
        float ym1 = r[k > 0 ? k - 1 : 0];
        float y0  = r[k];
        float y1  = r[k + 1];
        float y2  = r[k < NK - 1 ? k + 2 : KNOTS - 1];
        float dm1 = (y0 - ym1) / h;
        float d0  = (y1 - y0) / h;
        float d1  = (y2 - y1) / h;
        float mk  = (k == 0)      ? pchip_edge(d0, d1)  : pchip_inner(dm1, d0);
        float mk1 = (k == NK - 1) ? pchip_edge(d0, dm1) : pchip_inner(d0, d1);
        float hm0 = h * mk, hm1 = h * mk1;
        float dy = y1 - y0;
        float c2 = 3.0f * dy - 2.0f * hm0 - hm1;
        float c3 = hm0 + hm1 - 2.0f * dy;
        acc += fmaf(u, fmaf(u, fmaf(u, c3, c2), hm0), y0);
    }
    out[b * DOUT + o] = acc + bias[o];
}

extern "C" void kernel_launch(void* const* d_in, const int* in_sizes, int n_in,
                              void* d_out, int out_size, void* d_ws, size_t ws_size,
                              hipStream_t stream) {
    const float* x    = (const float*)d_in[0];   // (B, DIN)
    const float* y    = (const float*)d_in[1];   // (DIN, DOUT, KNOTS)
    const float* bias = (const float*)d_in[2];   // (DOUT,)
    float* out        = (float*)d_out;           // (B, DOUT)

    const size_t need = (size_t)DIN * B_SZ * sizeof(uint2); // 1 MB

    if (ws_size >= need) {
        uint2* W = (uint2*)d_ws;
        prep_w<<<dim3((DIN * B_SZ) / 256), dim3(256), 0, stream>>>(x, W, bias, out);
        kan_fwd<<<dim3(DOUT * 4), dim3(512), 0, stream>>>(W, y, out);
    } else {
        kan_naive<<<dim3(B_SZ), dim3(256), 0, stream>>>(x, y, bias, out);
    }
}

// Round 12
// 105.937 us; speedup vs baseline: 1.0537x; 1.0116x over previous
//
#include <hip/hip_runtime.h>
#include <cstdint>
#include <cstddef>

// Problem constants (from reference)
#define B_SZ   512
#define DIN    256
#define DOUT   256
#define KNOTS  64
#define NK     63                 // intervals = KNOTS-1
#define HSTEP  (4.0f / 63.0f)
#define INV_H  15.75f             // exact in f32

#define IHALF  128                // input dims per forward block (2 halves)

typedef _Float16 h2f __attribute__((ext_vector_type(2)));

// Per-interval entry: {y0, y1-y0, h*m0, h*m1} as 4 x f16 = 8 B (LDS-resident).
struct __align__(8) Ent { h2f ydy; h2f hmm; };
static_assert(sizeof(Ent) == 8, "Ent must be 8 bytes");

#if defined(__has_builtin)
#  if __has_builtin(__builtin_amdgcn_fdot2)
#    define HAVE_FDOT2 1
#  endif
#endif

static __device__ __forceinline__ float dot2acc(h2f a, h2f b, float acc) {
#ifdef HAVE_FDOT2
    return __builtin_amdgcn_fdot2(a, b, acc, false);
#else
    return acc + (float)a.x * (float)b.x + (float)a.y * (float)b.y;
#endif
}

static __device__ __forceinline__ unsigned f16bits(float v) {
    return (unsigned)__builtin_bit_cast(unsigned short, (_Float16)v);
}

// ---- PCHIP slope helpers (reference semantics, f32 exact) ----
static __device__ __forceinline__ float pchip_edge(float dA, float dB) {
    float m = 0.5f * (3.0f * dA - dB);
    if (m * dA <= 0.0f) {
        m = 0.0f;
    } else if (dA * dB < 0.0f && fabsf(m) > 3.0f * fabsf(dA)) {
        m = 3.0f * dA;
    }
    return m;
}

static __device__ __forceinline__ float pchip_inner(float d0, float d1) {
    if (d0 * d1 > 0.0f) {
        float denom = d0 + d1;
        if (fabsf(denom) < 1e-12f) return 0.0f;
        return 2.0f * d0 * d1 / denom;
    }
    return 0.0f;
}

// ---- Kernel A: packed per-(b,i) records + out = bias ----
// W[i*512 + b] = uint2{ (h01<<16)|k , (h11<<16)|h10 }  (8 B, 1 MB total).
// x-read coalesced (g = b*256+i is x's own layout); W store scattered but
// stores don't stall; out=bias init coalesced.
__global__ __launch_bounds__(256) void prep_w(const float* __restrict__ x,
                                              uint2* __restrict__ W,
                                              const float* __restrict__ bias,
                                              float* __restrict__ out) {
    const int g = blockIdx.x * 256 + threadIdx.x;   // 0..131071 = b*256 + i
    const int i = g & 255;

    float xv = x[g];                                // coalesced
    float xc = fminf(fmaxf(xv, -2.0f), 2.0f);
    float tv = (xc + 2.0f) * INV_H;
    int k = (int)tv;                                // tv >= 0
    k = k > NK - 1 ? NK - 1 : k;
    float u   = tv - (float)k;
    float u2  = u * u;
    float um1 = u - 1.0f;
    float c1  = u2 * (3.0f - 2.0f * u);             // h01
    float c2  = u * um1 * um1;                      // h10
    float c3  = u2 * um1;                           // h11

    const int b = g >> 8;
    uint2 w;
    w.x = (f16bits(c1) << 16) | (unsigned)k;        // {h01 | k}
    w.y = (f16bits(c3) << 16) | f16bits(c2);        // {h11 | h10}
    W[i * 512 + b] = w;

    out[g] = bias[i];                               // out[b][o] = bias[o]
}

// ---- Kernel B: forward (r9 structure, micro-tightened) ----
// Grid 512 = 256 o x 2 i-halves; 512 threads = one sample b each.
// LDS 63 KB Ent table (b64 gather, stride NK=63), built once per (i,o) in the
// prologue (now float4-vectorized). Inner loop per term: uint2 W load
// (coalesced, L2-hot) + v_and (k) + ds_read_b64 + v_and_or ({1,h01} rebuild)
// + 2x v_dot2_f32_f16. No launch-bounds clamp (r10 spill lesson).
__global__ __launch_bounds__(512) void kan_fwd(const uint2* __restrict__ W,
                                               const float* __restrict__ y,
                                               float* __restrict__ out) {
    __shared__ Ent ents[IHALF * NK];       // 64,512 B

    const int bid   = blockIdx.x;
    const int o     = bid >> 1;
    const int ihalf = bid & 1;
    const int t     = threadIdx.x;

    // ---- Prologue: build Ent table, 4 threads per input dim ----
    {
        const int il = t >> 2;             // 0..127
        const int q  = t & 3;              // strip: intervals k0..k0+15
        const int k0 = q * 16;
        const int ig = ihalf * IHALF + il;
        const float* row = y + ((size_t)ig * DOUT + o) * KNOTS;
        const float4* row4 = (const float4*)row;

        // ys[0..18] = y[k0-1 .. k0+17] clamped; body via 4 aligned float4.
        float ys[19];
        ys[0] = row[k0 > 0 ? k0 - 1 : 0];
#pragma unroll
        for (int z = 0; z < 4; ++z) {
            float4 v = row4[q * 4 + z];
            ys[1 + 4 * z + 0] = v.x;
            ys[1 + 4 * z + 1] = v.y;
            ys[1 + 4 * z + 2] = v.z;
            ys[1 + 4 * z + 3] = v.w;
        }
        ys[17] = row[k0 + 16 < KNOTS ? k0 + 16 : KNOTS - 1];
        ys[18] = row[k0 + 17 < KNOTS ? k0 + 17 : KNOTS - 1];

        float dd[18];                      // dd[u] = d[k0-1+u] (dup-clamp -> 0)
#pragma unroll
        for (int u = 0; u < 18; ++u) dd[u] = (ys[u + 1] - ys[u]) * INV_H;

        const int cnt = (q == 3) ? 15 : 16;  // last strip ends at k=62
#pragma unroll
        for (int n = 0; n < 16; ++n) {
            if (n < cnt) {
                const int k = k0 + n;
                float d_m1 = dd[n];
                float d_0  = dd[n + 1];
                float d_p1 = dd[n + 2];
                float mk  = pchip_inner(d_m1, d_0);
                if (k == 0)      mk  = pchip_edge(d_0, d_p1);
                float mk1 = pchip_inner(d_0, d_p1);
                if (k == NK - 1) mk1 = pchip_edge(d_0, d_m1);
                float y0 = ys[n + 1];
                float y1 = ys[n + 2];
                Ent e;
                e.ydy.x = (_Float16)y0;
                e.ydy.y = (_Float16)(y1 - y0);
                e.hmm.x = (_Float16)(HSTEP * mk);
                e.hmm.y = (_Float16)(HSTEP * mk1);
                ents[il * NK + k] = e;
            }
        }
    }
    __syncthreads();

    // ---- Main loop: one sample per thread, 128 terms ----
    const int b = t;
    const uint2* wp = W + (size_t)(ihalf * IHALF) * 512 + b;

    float acc = 0.0f;
#pragma unroll 8
    for (int il = 0; il < IHALF; ++il) {
        uint2 w = wp[(size_t)il * 512];             // coalesced 8 B, L2-hot
        const int k = (int)(w.x & 63u);
        Ent e = ents[il * NK + k];                  // single ds_read_b64 gather
        h2f w01 = __builtin_bit_cast(h2f, (w.x & 0xFFFF0000u) | 0x3C00u); // {1,h01}
        h2f w23 = __builtin_bit_cast(h2f, w.y);                           // {h10,h11}
        acc = dot2acc(e.ydy, w01, acc);             // y0*1 + dy*h01
        acc = dot2acc(e.hmm, w23, acc);             // hm0*h10 + hm1*h11
    }
    atomicAdd(&out[b * DOUT + o], acc);
}

// ---- Fallback: no-workspace path (only if ws_size is too small) ----
__global__ __launch_bounds__(256) void kan_naive(const float* __restrict__ x,
                                                 const float* __restrict__ y,
                                                 const float* __restrict__ bias,
                                                 float* __restrict__ out) {
    __shared__ int   sk[DIN];
    __shared__ float su[DIN];

    const int b   = blockIdx.x;
    const int tid = threadIdx.x;
    const float h = HSTEP;

    {
        float xv = x[b * DIN + tid];
        float xc = fminf(fmaxf(xv, -2.0f), 2.0f);
        float t  = (xc + 2.0f) / h;
        int k = (int)floorf(t);
        k = k < 0 ? 0 : (k > NK - 1 ? NK - 1 : k);
        sk[tid] = k;
        su[tid] = t - (float)k;
    }
    __syncthreads();

    const int o = tid;
    float acc = 0.0f;
    for (int i = 0; i < DIN; ++i) {
        int   k = sk[i];
        float u = su[i];
        const float* r = y + ((size_t)i * DOUT + o) * KNOTS;
        float ym1 = r[k > 0 ? k - 1 : 0];
        float y0  = r[k];
        float y1  = r[k + 1];
        float y2  = r[k < NK - 1 ? k + 2 : KNOTS - 1];
        float dm1 = (y0 - ym1) / h;
        float d0  = (y1 - y0) / h;
        float d1  = (y2 - y1) / h;
        float mk  = (k == 0)      ? pchip_edge(d0, d1)  : pchip_inner(dm1, d0);
        float mk1 = (k == NK - 1) ? pchip_edge(d0, dm1) : pchip_inner(d0, d1);
        float hm0 = h * mk, hm1 = h * mk1;
        float dy = y1 - y0;
        float c2 = 3.0f * dy - 2.0f * hm0 - hm1;
        float c3 = hm0 + hm1 - 2.0f * dy;
        acc += fmaf(u, fmaf(u, fmaf(u, c3, c2), hm0), y0);
    }
    out[b * DOUT + o] = acc + bias[o];
}

extern "C" void kernel_launch(void* const* d_in, const int* in_sizes, int n_in,
                              void* d_out, int out_size, void* d_ws, size_t ws_size,
                              hipStream_t stream) {
    const float* x    = (const float*)d_in[0];   // (B, DIN)
    const float* y    = (const float*)d_in[1];   // (DIN, DOUT, KNOTS)
    const float* bias = (const float*)d_in[2];   // (DOUT,)
    float* out        = (float*)d_out;           // (B, DOUT)

    const size_t need = (size_t)DIN * B_SZ * sizeof(uint2); // 1 MB

    if (ws_size >= need) {
        uint2* W = (uint2*)d_ws;
        prep_w<<<dim3((DIN * B_SZ) / 256), dim3(256), 0, stream>>>(x, W, bias, out);
        kan_fwd<<<dim3(DOUT * 2), dim3(512), 0, stream>>>(W, y, out);
    } else {
        kan_naive<<<dim3(B_SZ), dim3(256), 0, stream>>>(x, y, bias, out);
    }
}

// Round 13
// 97.138 us; speedup vs baseline: 1.1492x; 1.0906x over previous
//
#include <hip/hip_runtime.h>
#include <cstdint>
#include <cstddef>

// Problem constants (from reference)
#define B_SZ   512
#define DIN    256
#define DOUT   256
#define KNOTS  64
#define NK     63                 // intervals = KNOTS-1
#define HSTEP  (4.0f / 63.0f)
#define INV_H  15.75f             // exact in f32

#define IHALF  128                // input dims per forward block (2 halves)

typedef _Float16 h2f __attribute__((ext_vector_type(2)));

// Per-interval entry: {y0, y1-y0, h*m0, h*m1} as 4 x f16 = 8 B (LDS-resident).
struct __align__(8) Ent { h2f ydy; h2f hmm; };
static_assert(sizeof(Ent) == 8, "Ent must be 8 bytes");

#if defined(__has_builtin)
#  if __has_builtin(__builtin_amdgcn_fdot2)
#    define HAVE_FDOT2 1
#  endif
#endif

static __device__ __forceinline__ float dot2acc(h2f a, h2f b, float acc) {
#ifdef HAVE_FDOT2
    return __builtin_amdgcn_fdot2(a, b, acc, false);
#else
    return acc + (float)a.x * (float)b.x + (float)a.y * (float)b.y;
#endif
}

static __device__ __forceinline__ unsigned short f16b(float v) {
    return __builtin_bit_cast(unsigned short, (_Float16)v);
}
static __device__ __forceinline__ _Float16 b16f(unsigned short v) {
    return __builtin_bit_cast(_Float16, v);
}

// ---- PCHIP slope helpers (reference semantics, f32 exact) ----
static __device__ __forceinline__ float pchip_edge(float dA, float dB) {
    float m = 0.5f * (3.0f * dA - dB);
    if (m * dA <= 0.0f) {
        m = 0.0f;
    } else if (dA * dB < 0.0f && fabsf(m) > 3.0f * fabsf(dA)) {
        m = 3.0f * dA;
    }
    return m;
}

static __device__ __forceinline__ float pchip_inner(float d0, float d1) {
    if (d0 * d1 > 0.0f) {
        float denom = d0 + d1;
        if (fabsf(denom) < 1e-12f) return 0.0f;
        return 2.0f * d0 * d1 / denom;
    }
    return 0.0f;
}

// ---- Kernel A: per-(b,i) records {k, h01, h10, h11} + out = bias ----
// W[i*512 + b], 8 B each (1 MB total, L2-resident for the forward).
// Computed exactly ONCE per (b,i) — shared by all 256 output dims.
// Scattered x-read (L2-absorbed, 512 KB) + COALESCED W-store (r12 lesson:
// the flipped layout with scattered 2 KB-stride stores cost ~8 us).
__global__ __launch_bounds__(256) void prep_w(const float* __restrict__ x,
                                              ushort4* __restrict__ W,
                                              const float* __restrict__ bias,
                                              float* __restrict__ out) {
    const int g = blockIdx.x * 256 + threadIdx.x;   // 0..131071
    const int i = g >> 9;
    const int b = g & 511;

    float xv = x[b * DIN + i];                      // strided; L2-amortized
    float xc = fminf(fmaxf(xv, -2.0f), 2.0f);
    float tv = (xc + 2.0f) * INV_H;
    int k = (int)tv;                                // tv >= 0
    k = k > NK - 1 ? NK - 1 : k;
    float u   = tv - (float)k;
    float u2  = u * u;
    float um1 = u - 1.0f;
    float c1  = u2 * (3.0f - 2.0f * u);             // h01
    float c2  = u * um1 * um1;                      // h10
    float c3  = u2 * um1;                           // h11

    ushort4 w;
    w.x = (unsigned short)k;
    w.y = f16b(c1);
    w.z = f16b(c2);
    w.w = f16b(c3);
    W[g] = w;                                       // coalesced 8 B store

    out[g] = bias[g & (DOUT - 1)];                  // out[b'][o] = bias[o]
}

// ---- Kernel B: forward, Ent table built in LDS per (o, i-half) ----
// Grid 512 = 256 o x 2 i-halves; 512 threads = one sample b each.
// Prologue: 128 x 63 Ent entries (63 KB LDS), slopes computed once per (i,o)
// from y rows via L1/L2 (block slice = 32 KB). Main loop per term:
// coalesced 8 B W-read (L2-resident 1 MB) + ds_read_b64 + 2x fdot2.
// No global table, no scattered global gathers. 2 blocks/CU (126 KB LDS).
__global__ __launch_bounds__(512) void kan_fwd(const ushort4* __restrict__ W,
                                               const float* __restrict__ y,
                                               float* __restrict__ out) {
    __shared__ Ent ents[IHALF * NK];       // 64,512 B

    const int bid   = blockIdx.x;
    const int o     = bid >> 1;
    const int ihalf = bid & 1;
    const int t     = threadIdx.x;

    // ---- Prologue: build Ent table, 4 threads per input dim ----
    {
        const int il = t >> 2;             // 0..127
        const int q  = t & 3;              // strip
        const int k0 = q * 16;
        const int ig = ihalf * IHALF + il;
        const float* row = y + ((size_t)ig * DOUT + o) * KNOTS;

        float ys[19];                      // y[k0-1 .. k0+17], clamped
#pragma unroll
        for (int u = 0; u < 19; ++u) {
            int kk = k0 - 1 + u;
            kk = kk < 0 ? 0 : (kk > KNOTS - 1 ? KNOTS - 1 : kk);
            ys[u] = row[kk];               // scalar, L1/L2-cached
        }
        float dd[18];
#pragma unroll
        for (int u = 0; u < 18; ++u) dd[u] = (ys[u + 1] - ys[u]) * INV_H;

        const int cnt = (q == 3) ? 15 : 16;
#pragma unroll
        for (int n = 0; n < 16; ++n) {
            if (n < cnt) {
                const int k = k0 + n;
                float d_m1 = dd[n];        // d[k-1] (0-dup at k=0, overridden)
                float d_0  = dd[n + 1];    // d[k]
                float d_p1 = dd[n + 2];    // d[k+1] (0-dup at k=62, overridden)
                float mk  = pchip_inner(d_m1, d_0);
                if (k == 0)      mk  = pchip_edge(d_0, d_p1);
                float mk1 = pchip_inner(d_0, d_p1);
                if (k == NK - 1) mk1 = pchip_edge(d_0, d_m1);
                float y0 = ys[n + 1];
                float y1 = ys[n + 2];
                Ent e;
                e.ydy.x = (_Float16)y0;
                e.ydy.y = (_Float16)(y1 - y0);
                e.hmm.x = (_Float16)(HSTEP * mk);
                e.hmm.y = (_Float16)(HSTEP * mk1);
                ents[il * NK + k] = e;
            }
        }
    }
    __syncthreads();

    // ---- Main loop: one sample per thread, 128 terms ----
    const int b = t;
    const ushort4* wp = W + (size_t)(ihalf * IHALF) * 512 + b;

    float acc = 0.0f;
#pragma unroll 8
    for (int il = 0; il < IHALF; ++il) {
        ushort4 w = wp[(size_t)il * 512];           // coalesced 8 B, L2-hot
        const int k = w.x;
        Ent e = ents[il * NK + k];                  // ds_read_b64, mostly bcast
        h2f w01, w23;
        w01.x = (_Float16)1.0f;
        w01.y = b16f(w.y);
        w23.x = b16f(w.z);
        w23.y = b16f(w.w);
        acc = dot2acc(e.ydy, w01, acc);             // y0 + dy*h01
        acc = dot2acc(e.hmm, w23, acc);             // hm0*h10 + hm1*h11
    }
    atomicAdd(&out[b * DOUT + o], acc);
}

// ---- Fallback: no-workspace path (only if ws_size is too small) ----
__global__ __launch_bounds__(256) void kan_naive(const float* __restrict__ x,
                                                 const float* __restrict__ y,
                                                 const float* __restrict__ bias,
                                                 float* __restrict__ out) {
    __shared__ int   sk[DIN];
    __shared__ float su[DIN];

    const int b   = blockIdx.x;
    const int tid = threadIdx.x;
    const float h = HSTEP;

    {
        float xv = x[b * DIN + tid];
        float xc = fminf(fmaxf(xv, -2.0f), 2.0f);
        float t  = (xc + 2.0f) / h;
        int k = (int)floorf(t);
        k = k < 0 ? 0 : (k > NK - 1 ? NK - 1 : k);
        sk[tid] = k;
        su[tid] = t - (float)k;
    }
    __syncthreads();

    const int o = tid;
    float acc = 0.0f;
    for (int i = 0; i < DIN; ++i) {
        int   k = sk[i];
        float u = su[i];
        const float* r = y + ((size_t)i * DOUT + o) * KNOTS;
        float ym1 = r[k > 0 ? k - 1 : 0];
        float y0  = r[k];
        float y1  = r[k + 1];
        float y2  = r[k < NK - 1 ? k + 2 : KNOTS - 1];
        float dm1 = (y0 - ym1) / h;
        float d0  = (y1 - y0) / h;
        float d1  = (y2 - y1) / h;
        float mk  = (k == 0)      ? pchip_edge(d0, d1)  : pchip_inner(dm1, d0);
        float mk1 = (k == NK - 1) ? pchip_edge(d0, dm1) : pchip_inner(d0, d1);
        float hm0 = h * mk, hm1 = h * mk1;
        float dy = y1 - y0;
        float c2 = 3.0f * dy - 2.0f * hm0 - hm1;
        float c3 = hm0 + hm1 - 2.0f * dy;
        acc += fmaf(u, fmaf(u, fmaf(u, c3, c2), hm0), y0);
    }
    out[b * DOUT + o] = acc + bias[o];
}

extern "C" void kernel_launch(void* const* d_in, const int* in_sizes, int n_in,
                              void* d_out, int out_size, void* d_ws, size_t ws_size,
                              hipStream_t stream) {
    const float* x    = (const float*)d_in[0];   // (B, DIN)
    const float* y    = (const float*)d_in[1];   // (DIN, DOUT, KNOTS)
    const float* bias = (const float*)d_in[2];   // (DOUT,)
    float* out        = (float*)d_out;           // (B, DOUT)

    const size_t need = (size_t)DIN * B_SZ * sizeof(ushort4); // 1 MB

    if (ws_size >= need) {
        ushort4* W = (ushort4*)d_ws;
        prep_w<<<dim3((DIN * B_SZ) / 256), dim3(256), 0, stream>>>(x, W, bias, out);
        kan_fwd<<<dim3(DOUT * 2), dim3(512), 0, stream>>>(W, y, out);
    } else {
        kan_naive<<<dim3(B_SZ), dim3(256), 0, stream>>>(x, y, bias, out);
    }
}